// Round 1
// baseline (270.887 us; speedup 1.0000x reference)
//
#include <hip/hip_runtime.h>
#include <hip/hip_bf16.h>
#include <hip/hip_fp16.h>

#define B_ 8
#define N_ 1024
#define D_ 256
#define H_ 8
#define HD_ 512   // H_*64

typedef _Float16 f16;
typedef _Float16 f16x8 __attribute__((ext_vector_type(8)));
typedef _Float16 f16x4 __attribute__((ext_vector_type(4)));
typedef float f32x4 __attribute__((ext_vector_type(4)));

// ---------------------------------------------------------------------------
// Kernel 1: fused QKV projection.  C = X(8192,256) @ [Wq|Wk|Wv](256,1536)
// Output: Qh,Kh as (B,H,N,64) f16;  V transposed as Vt (B,H,64,N) f16.
// Block tile: 64 rows x 256 cols, 4 waves (each wave: 16 rows x 256 cols).
// ---------------------------------------------------------------------------
__global__ __launch_bounds__(256) void qkv_kernel(
    const float* __restrict__ X,
    const float* __restrict__ Wq, const float* __restrict__ Wk,
    const float* __restrict__ Wv,
    f16* __restrict__ Qh, f16* __restrict__ Kh, f16* __restrict__ Vt)
{
    __shared__ f16 BsT[256][40];   // [col][k] transposed, stride 40 (80B, 16B-mult)
    const int tid = threadIdx.x;
    const int wv = tid >> 6, lane = tid & 63;
    const int g = lane >> 4, li = lane & 15;
    const int rt = blockIdx.x;     // 0..127  (64-row tiles)
    const int ct = blockIdx.y;     // 0..5    (256-col tiles)
    const int row0 = rt * 64;
    const int c0 = ct * 256;
    const int m = c0 >> 9;                 // 0=Q,1=K,2=V
    const int cw0 = c0 & 511;              // col offset within that W
    const float* Wsel = (m == 0) ? Wq : (m == 1) ? Wk : Wv;

    f32x4 acc[16] = {};
    const int arow = row0 + wv * 16 + li;
    const float* Xrow = X + (size_t)arow * D_;

    for (int k0 = 0; k0 < D_; k0 += 32) {
        // stage W[k0:k0+32, c0:c0+256] transposed into LDS (coalesced reads)
        for (int i = tid; i < 32 * 256; i += 256) {
            int k = i >> 8, c = i & 255;
            BsT[c][k] = (f16)Wsel[(size_t)(k0 + k) * HD_ + cw0 + c];
        }
        __syncthreads();
        // A fragment: 8 contiguous k per lane (kappa'(g,j)=8g+j), fp32->fp16
        f32x4 a0 = *reinterpret_cast<const f32x4*>(Xrow + k0 + g * 8);
        f32x4 a1 = *reinterpret_cast<const f32x4*>(Xrow + k0 + g * 8 + 4);
        f16x8 af;
        for (int j = 0; j < 4; ++j) { af[j] = (f16)a0[j]; af[4 + j] = (f16)a1[j]; }
        for (int fc = 0; fc < 16; ++fc) {
            f16x8 bf = *reinterpret_cast<const f16x8*>(&BsT[fc * 16 + li][g * 8]);
            acc[fc] = __builtin_amdgcn_mfma_f32_16x16x32_f16(af, bf, acc[fc], 0, 0, 0);
        }
        __syncthreads();
    }
    // epilogue: C layout row=(lane>>4)*4+j, col=lane&15
    const int b = row0 >> 10;
    const int nloc = (row0 & 1023) + wv * 16 + g * 4;   // row within batch
    for (int fc = 0; fc < 16; ++fc) {
        int cw = cw0 + fc * 16 + li;
        int h = cw >> 6, dk = cw & 63;
        if (m < 2) {
            f16* dst = (m == 0 ? Qh : Kh) + ((size_t)(b * H_ + h) * N_ + nloc) * 64 + dk;
            for (int j = 0; j < 4; ++j) dst[(size_t)j * 64] = (f16)acc[fc][j];
        } else {
            f16x4 v4;
            for (int j = 0; j < 4; ++j) v4[j] = (f16)acc[fc][j];
            *reinterpret_cast<f16x4*>(Vt + ((size_t)(b * H_ + h) * 64 + dk) * N_ + nloc) = v4;
        }
    }
}

// ---------------------------------------------------------------------------
// Kernel 2: flash attention per (b, h, 64-row s-tile).  4 independent waves,
// each owns 16 s-rows.  Online softmax; P re-fragmented through per-wave LDS.
// ---------------------------------------------------------------------------
__global__ __launch_bounds__(256) void attn_kernel(
    const f16* __restrict__ Qh, const f16* __restrict__ Kh,
    const f16* __restrict__ Vt,
    const float* __restrict__ mask, const float* __restrict__ dw,
    f16* __restrict__ AO)
{
    __shared__ f16 Ps[4][16][72];   // per-wave P tile, stride 72 (144B, 16B-mult)
    const int tid = threadIdx.x;
    const int wv = tid >> 6, lane = tid & 63;
    const int g = lane >> 4, li = lane & 15;
    const int bid = blockIdx.x;
    const int st = bid & 15, h = (bid >> 4) & 7, b = bid >> 7;
    const int s0 = st * 64 + wv * 16;      // this wave's first s-row (within batch)

    const f16* Qbase = Qh + (size_t)(b * H_ + h) * N_ * 64;
    const f16* Kbase = Kh + (size_t)(b * H_ + h) * N_ * 64;
    const f16* Vbase = Vt + (size_t)(b * H_ + h) * 64 * N_;
    const float* mbase = mask + (size_t)b * N_ * N_;
    const float* dwb = dw + b * N_;

    f16x8 qf[2];
    qf[0] = *reinterpret_cast<const f16x8*>(Qbase + (size_t)(s0 + li) * 64 + g * 8);
    qf[1] = *reinterpret_cast<const f16x8*>(Qbase + (size_t)(s0 + li) * 64 + 32 + g * 8);

    f32x4 of[4] = {};
    float m_run[4], l_run[4];
    for (int j = 0; j < 4; ++j) { m_run[j] = -1e30f; l_run[j] = 0.f; }

    for (int tt = 0; tt < 16; ++tt) {
        const int t0 = tt * 64;
        f32x4 s[4] = {};
        for (int fc = 0; fc < 4; ++fc) {
            const f16* kp = Kbase + (size_t)(t0 + fc * 16 + li) * 64 + g * 8;
            f16x8 kf0 = *reinterpret_cast<const f16x8*>(kp);
            f16x8 kf1 = *reinterpret_cast<const f16x8*>(kp + 32);
            s[fc] = __builtin_amdgcn_mfma_f32_16x16x32_f16(qf[0], kf0, s[fc], 0, 0, 0);
            s[fc] = __builtin_amdgcn_mfma_f32_16x16x32_f16(qf[1], kf1, s[fc], 0, 0, 0);
        }
        // logits = (S/8 + (1-mask)*NEG) * dw[t];  C layout: row g*4+j, col li
        float pj[4][4];
        float mt[4] = {-1e30f, -1e30f, -1e30f, -1e30f};
        for (int fc = 0; fc < 4; ++fc) {
            float dwv = dwb[t0 + fc * 16 + li];
            const float* mrow = mbase + (size_t)(s0 + g * 4) * N_ + t0 + fc * 16 + li;
            for (int j = 0; j < 4; ++j) {
                float mv = mrow[(size_t)j * N_];
                float lg = (s[fc][j] * 0.125f + (1.f - mv) * (-1e9f)) * dwv;
                pj[fc][j] = lg;
                mt[j] = fmaxf(mt[j], lg);
            }
        }
        for (int j = 0; j < 4; ++j) {
            mt[j] = fmaxf(mt[j], __shfl_xor(mt[j], 1));
            mt[j] = fmaxf(mt[j], __shfl_xor(mt[j], 2));
            mt[j] = fmaxf(mt[j], __shfl_xor(mt[j], 4));
            mt[j] = fmaxf(mt[j], __shfl_xor(mt[j], 8));
        }
        float alpha[4];
        for (int j = 0; j < 4; ++j) {
            float mn = fmaxf(m_run[j], mt[j]);
            alpha[j] = __expf(m_run[j] - mn);
            m_run[j] = mn;
        }
        float rs[4] = {0.f, 0.f, 0.f, 0.f};
        for (int fc = 0; fc < 4; ++fc)
            for (int j = 0; j < 4; ++j) {
                float p = __expf(pj[fc][j] - m_run[j]);
                pj[fc][j] = p;
                rs[j] += p;
            }
        for (int j = 0; j < 4; ++j) {
            rs[j] += __shfl_xor(rs[j], 1);
            rs[j] += __shfl_xor(rs[j], 2);
            rs[j] += __shfl_xor(rs[j], 4);
            rs[j] += __shfl_xor(rs[j], 8);
            l_run[j] = l_run[j] * alpha[j] + rs[j];
        }
        for (int fc = 0; fc < 4; ++fc)
            for (int j = 0; j < 4; ++j) of[fc][j] *= alpha[j];
        // P -> LDS (C layout) -> A fragments (row=li, k=t_local)
        for (int fc = 0; fc < 4; ++fc)
            for (int j = 0; j < 4; ++j)
                Ps[wv][g * 4 + j][fc * 16 + li] = (f16)pj[fc][j];
        // same-wave DS ordering: no barrier needed (per-wave buffer)
        f16x8 pf0 = *reinterpret_cast<const f16x8*>(&Ps[wv][li][g * 8]);
        f16x8 pf1 = *reinterpret_cast<const f16x8*>(&Ps[wv][li][32 + g * 8]);
        for (int fc = 0; fc < 4; ++fc) {
            const f16* vp = Vbase + (size_t)(fc * 16 + li) * N_ + t0 + g * 8;
            f16x8 vf0 = *reinterpret_cast<const f16x8*>(vp);
            f16x8 vf1 = *reinterpret_cast<const f16x8*>(vp + 32);
            of[fc] = __builtin_amdgcn_mfma_f32_16x16x32_f16(pf0, vf0, of[fc], 0, 0, 0);
            of[fc] = __builtin_amdgcn_mfma_f32_16x16x32_f16(pf1, vf1, of[fc], 0, 0, 0);
        }
    }
    for (int j = 0; j < 4; ++j) {
        float inv = 1.f / l_run[j];
        int srow = s0 + g * 4 + j;
        f16* dst = AO + ((size_t)b * N_ + srow) * HD_ + h * 64;
        for (int fc = 0; fc < 4; ++fc)
            dst[fc * 16 + li] = (f16)(of[fc][j] * inv);
    }
}

// ---------------------------------------------------------------------------
// Kernel 3: out = AO(8192,512) @ Wo(512,256) + bo.  64x64 tiles.
// ---------------------------------------------------------------------------
__global__ __launch_bounds__(256) void proj_kernel(
    const f16* __restrict__ AO,
    const float* __restrict__ Wo, const float* __restrict__ bo,
    float* __restrict__ out)
{
    __shared__ f16 BsT[64][40];
    const int tid = threadIdx.x;
    const int wv = tid >> 6, lane = tid & 63;
    const int g = lane >> 4, li = lane & 15;
    const int row0 = blockIdx.x * 64, c0 = blockIdx.y * 64;

    f32x4 acc[4] = {};
    const f16* Arow = AO + (size_t)(row0 + wv * 16 + li) * HD_;

    for (int k0 = 0; k0 < HD_; k0 += 32) {
        for (int i = tid; i < 32 * 64; i += 256) {
            int k = i >> 6, c = i & 63;
            BsT[c][k] = (f16)Wo[(size_t)(k0 + k) * D_ + c0 + c];
        }
        __syncthreads();
        f16x8 af = *reinterpret_cast<const f16x8*>(Arow + k0 + g * 8);
        for (int fc = 0; fc < 4; ++fc) {
            f16x8 bf = *reinterpret_cast<const f16x8*>(&BsT[fc * 16 + li][g * 8]);
            acc[fc] = __builtin_amdgcn_mfma_f32_16x16x32_f16(af, bf, acc[fc], 0, 0, 0);
        }
        __syncthreads();
    }
    for (int fc = 0; fc < 4; ++fc) {
        int c = c0 + fc * 16 + li;
        float bias = bo[c];
        for (int j = 0; j < 4; ++j) {
            int r = row0 + wv * 16 + g * 4 + j;
            out[(size_t)r * D_ + c] = acc[fc][j] + bias;
        }
    }
}

extern "C" void kernel_launch(void* const* d_in, const int* in_sizes, int n_in,
                              void* d_out, int out_size, void* d_ws, size_t ws_size,
                              hipStream_t stream) {
    const float* X    = (const float*)d_in[0];
    const float* mask = (const float*)d_in[1];
    const float* dwv  = (const float*)d_in[2];
    const float* Wq   = (const float*)d_in[3];
    const float* Wk   = (const float*)d_in[4];
    const float* Wv   = (const float*)d_in[5];
    const float* Wo   = (const float*)d_in[6];
    const float* bo   = (const float*)d_in[7];
    float* out = (float*)d_out;

    const size_t per = (size_t)B_ * H_ * N_ * 64;   // 4M halves each
    f16* Qh = (f16*)d_ws;
    f16* Kh = Qh + per;
    f16* Vt = Kh + per;
    f16* AO = Vt + per;

    qkv_kernel<<<dim3(128, 6), 256, 0, stream>>>(X, Wq, Wk, Wv, Qh, Kh, Vt);
    attn_kernel<<<dim3(1024), 256, 0, stream>>>(Qh, Kh, Vt, mask, dwv, AO);
    proj_kernel<<<dim3(128, 4), 256, 0, stream>>>(AO, Wo, bo, out);
}